// Round 8
// baseline (166.622 us; speedup 1.0000x reference)
//
#include <hip/hip_runtime.h>
#include <hip/hip_bf16.h>

// LossVariance — B=16, C=32, H=W=512, L=64.
// loss = mean_b [ sum_{l!=0} var_sum(b,l) / (num_unique_b + 1e-8) ]
// var_sum(b,l) = (q - sum_c s_c^2/cnt) / (cnt-1), cnt>1 else 0
//   s[b,l,c] = sum_{p: t=l} x[b,c,p]   -> one-hot GEMM on MFMA
//   q[b,l]   = sum_c ss[b,l,c]         -> same MFMAs, B = bf16(x*x)
//   cnt      = LDS histogram
// R8: x staged through LDS via global_load_lds with row-burst (512B/row/visit)
//     coalesced reads -> DRAM-friendly sequential bursts; granule XOR-swizzle
//     (g ^= ch&7) on both sides for conflict-free ds_read_b128; counted-vmcnt
//     double-buffer pipeline (T3-lite). Compute path identical to R6/R7.

#define LBL 64
#define CH 32
constexpr int PIX   = 512 * 512;
constexpr int BATCH = 16;
constexpr int BPB   = 64;                  // pixel-blocks per batch
constexpr int TPB   = 256;                 // 4 waves
constexpr int PPB   = PIX / BPB;           // 4096 pixels per block
constexpr int CHUNK_PIX = 128;             // pixels per staged chunk
constexpr int NCHUNK    = PPB / CHUNK_PIX; // 32 chunks per block
constexpr int CHUNK_F   = CH * CHUNK_PIX;  // 4096 floats = 16KB per chunk

typedef __attribute__((ext_vector_type(8))) short    bf16x8;
typedef __attribute__((ext_vector_type(4))) float    f32x4;
typedef __attribute__((ext_vector_type(4))) unsigned u32x4;

typedef __attribute__((address_space(3))) void       lds_void_t;
typedef const __attribute__((address_space(1))) void g_void_t;

// ws layout (floats): s_g[B][L][CH] | q_g[B][L] | c_g[B][L]
constexpr int Q_OFF     = BATCH * LBL * CH;        // 32768
constexpr int C_OFF     = Q_OFF + BATCH * LBL;     // 33792
constexpr int WS_FLOATS = C_OFF + BATCH * LBL;     // 34816 (136 KiB)

// pack two f32 -> one u32 of 2x bf16 (round-half-away): bf16 = hi16(bits+0x8000)
static __device__ __forceinline__ unsigned bfpair(float lo, float hi) {
    const unsigned ulo = __builtin_bit_cast(unsigned, lo) + 0x8000u;
    const unsigned uhi = __builtin_bit_cast(unsigned, hi) + 0x8000u;
    return __builtin_amdgcn_perm(uhi, ulo, 0x07060302u);
}
static __device__ __forceinline__ bf16x8 pack8r(f32x4 a, f32x4 b) {
    u32x4 w;
    w[0] = bfpair(a[0], a[1]);
    w[1] = bfpair(a[2], a[3]);
    w[2] = bfpair(b[0], b[1]);
    w[3] = bfpair(b[2], b[3]);
    return __builtin_bit_cast(bf16x8, w);
}

__global__ __launch_bounds__(TPB) void zero_ws(float* __restrict__ ws) {
    const int i = blockIdx.x * TPB + threadIdx.x;
    if (i < WS_FLOATS) ws[i] = 0.f;
}

__global__ __launch_bounds__(TPB, 3) void seg_onehot_mfma(
    const float* __restrict__ x, const int* __restrict__ tg,
    float* __restrict__ s_g, float* __restrict__ q_g, float* __restrict__ c_g)
{
    __shared__ float    xs[2][CHUNK_F];            // 32 KiB staged x (dbuf)
    __shared__ float    s_blk[LBL][CH + 1];        // 8.25 KiB
    __shared__ float    ss_blk[LBL][CH + 1];       // 8.25 KiB
    __shared__ unsigned c_hist[LBL];
    __shared__ __align__(16) unsigned char lab8[PPB];   // 4 KiB packed labels

    const int b    = blockIdx.y;
    const int tid  = threadIdx.x;
    const int wave = tid >> 6;
    const int lane = tid & 63;
    const int p0   = blockIdx.x * PPB;

    const int kgrp   = lane >> 4;          // K sub-block 0..3 (8 pixels each)
    const int lo     = lane & 15;          // A: label-in-tile / B: channel-in-tile
    const int h      = wave >> 1;          // pixel half of chunk
    const int ch_off = (wave & 1) * 16;    // channel half

    // staging geometry: wave w stages rows [8w,8w+8); instr j covers rows
    // 8w+2j,8w+2j+1 (lanes 0-31 / 32-63), each lane one 16B granule.
    // LDS is linear; global source is inverse-swizzled: granule gr of row r
    // holds global granule (gr ^ (r&7)).
    const float* sbase[4];
    #pragma unroll
    for (int j = 0; j < 4; ++j) {
        const int r  = wave * 8 + j * 2 + (lane >> 5);   // channel row 0..31
        const int gr = lane & 31;                        // granule in 512B row-chunk
        sbase[j] = x + (size_t)(b * CH + r) * PIX + p0 + ((gr ^ (r & 7)) << 2);
    }

#define STAGE(c, bi)                                                          \
    {                                                                         \
        _Pragma("unroll")                                                     \
        for (int j = 0; j < 4; ++j) {                                         \
            __builtin_amdgcn_global_load_lds(                                 \
                (g_void_t*)(sbase[j] + (c) * CHUNK_PIX),                      \
                (lds_void_t*)&xs[bi][wave * 1024 + j * 256], 16, 0, 0);       \
        }                                                                     \
    }

    // ---- zero LDS accumulators
    for (int i = tid; i < LBL * (CH + 1); i += TPB) {
        (&s_blk[0][0])[i]  = 0.f;
        (&ss_blk[0][0])[i] = 0.f;
    }
    if (tid < LBL) c_hist[tid] = 0u;
    __syncthreads();   // c_hist zeroed before ANY wave's atomics

    // ---- label pass: 16 labels/thread -> u8 pack + histogram
    const int* tb = tg + (size_t)b * PIX;
    {
        const int gbase = p0 + tid * 16;
        int4 lv[4];
        #pragma unroll
        for (int j = 0; j < 4; ++j)
            lv[j] = *reinterpret_cast<const int4*>(tb + gbase + j * 4);
        u32x4 pk;
        #pragma unroll
        for (int j = 0; j < 4; ++j)
            pk[j] = (unsigned)lv[j].x | ((unsigned)lv[j].y << 8) |
                    ((unsigned)lv[j].z << 16) | ((unsigned)lv[j].w << 24);
        *reinterpret_cast<u32x4*>(&lab8[tid * 16]) = pk;
        #pragma unroll
        for (int j = 0; j < 4; ++j) {
            atomicAdd(&c_hist[lv[j].x], 1u);
            atomicAdd(&c_hist[lv[j].y], 1u);
            atomicAdd(&c_hist[lv[j].z], 1u);
            atomicAdd(&c_hist[lv[j].w], 1u);
        }
    }
    __syncthreads();   // lab8 visible; all histogram loads consumed (vmcnt clean)

    // ---- prologue: two chunks in flight
    STAGE(0, 0)
    STAGE(1, 1)

    f32x4 acc_s[4], acc_q[4];
    #pragma unroll
    for (int m = 0; m < 4; ++m) {
        acc_s[m] = (f32x4){0.f, 0.f, 0.f, 0.f};
        acc_q[m] = (f32x4){0.f, 0.f, 0.f, 0.f};
    }

    const int crow = ch_off + lo;                    // this lane's channel row
    const float* xrow_base = &xs[0][crow * CHUNK_PIX];

    for (int t = 0; t < NCHUNK; ++t) {
        // wait for stage(t) only (stage(t+1)'s 4 loads stay in flight), then
        // barrier so all waves' stage(t) DMA writes are visible.
        if (t < NCHUNK - 1) {
            asm volatile("s_waitcnt vmcnt(4)\n\ts_barrier" ::: "memory");
        } else {
            asm volatile("s_waitcnt vmcnt(0)\n\ts_barrier" ::: "memory");
        }

        const int bi = t & 1;
        const float* xrow = xrow_base + bi * CHUNK_F;
        const unsigned char* lb = &lab8[t * CHUNK_PIX + h * 64 + kgrp * 8];

        #pragma unroll
        for (int st = 0; st < 2; ++st) {
            const uint2 L = *reinterpret_cast<const uint2*>(lb + st * 32);
            const int g0 = st * 8 + kgrp * 2;
            const f32x4 F0 = *reinterpret_cast<const f32x4*>(xrow + (((g0    ) ^ (crow & 7)) << 2));
            const f32x4 F1 = *reinterpret_cast<const f32x4*>(xrow + (((g0 + 1) ^ (crow & 7)) << 2));

            const bf16x8 bx = pack8r(F0, F1);
            const bf16x8 bq = pack8r(F0 * F0, F1 * F1);

            const unsigned e0 = (L.x      ) & 0xFFu;
            const unsigned e1 = (L.x >>  8) & 0xFFu;
            const unsigned e2 = (L.x >> 16) & 0xFFu;
            const unsigned e3 = (L.x >> 24);
            const unsigned e4 = (L.y      ) & 0xFFu;
            const unsigned e5 = (L.y >>  8) & 0xFFu;
            const unsigned e6 = (L.y >> 16) & 0xFFu;
            const unsigned e7 = (L.y >> 24);

            #pragma unroll
            for (int m = 0; m < 4; ++m) {
                const unsigned tgt = (unsigned)(lo + m * 16);
                u32x4 w;
                w[0] = ((e0 == tgt) ? 0x00003F80u : 0u) | ((e1 == tgt) ? 0x3F800000u : 0u);
                w[1] = ((e2 == tgt) ? 0x00003F80u : 0u) | ((e3 == tgt) ? 0x3F800000u : 0u);
                w[2] = ((e4 == tgt) ? 0x00003F80u : 0u) | ((e5 == tgt) ? 0x3F800000u : 0u);
                w[3] = ((e6 == tgt) ? 0x00003F80u : 0u) | ((e7 == tgt) ? 0x3F800000u : 0u);
                const bf16x8 am = __builtin_bit_cast(bf16x8, w);
                acc_s[m] = __builtin_amdgcn_mfma_f32_16x16x32_bf16(am, bx, acc_s[m], 0, 0, 0);
                acc_q[m] = __builtin_amdgcn_mfma_f32_16x16x32_bf16(am, bq, acc_q[m], 0, 0, 0);
            }
        }

        // all waves done reading buf bi (lgkm drained) before re-staging it
        asm volatile("s_waitcnt lgkmcnt(0)\n\ts_barrier" ::: "memory");
        if (t + 2 < NCHUNK) STAGE(t + 2, bi)
    }
#undef STAGE

    // ---- fragments -> block LDS (C/D: col=lane&15, row=(lane>>4)*4+r)
    #pragma unroll
    for (int m = 0; m < 4; ++m)
        #pragma unroll
        for (int r = 0; r < 4; ++r) {
            const int row = m * 16 + kgrp * 4 + r;
            const int col = ch_off + lo;
            unsafeAtomicAdd(&s_blk[row][col],  acc_s[m][r]);
            unsafeAtomicAdd(&ss_blk[row][col], acc_q[m][r]);
        }
    __syncthreads();

    // ---- flush block partials to global accumulators (atomic; ws pre-zeroed)
    float* sg = s_g + (size_t)b * LBL * CH;
    #pragma unroll
    for (int i = 0; i < 8; ++i) {
        const int idx = tid + i * TPB;          // 0..2047
        unsafeAtomicAdd(&sg[idx], s_blk[idx >> 5][idx & 31]);
    }
    if (tid < LBL) {
        float q = 0.f;
        #pragma unroll
        for (int c = 0; c < CH; ++c) q += ss_blk[tid][c];
        unsafeAtomicAdd(&q_g[b * LBL + tid], q);
        unsafeAtomicAdd(&c_g[b * LBL + tid], (float)c_hist[tid]);
    }
}

__global__ __launch_bounds__(1024) void finalize(
    const float* __restrict__ s_g, const float* __restrict__ q_g,
    const float* __restrict__ c_g, float* __restrict__ out)
{
    const int t = threadIdx.x;        // 0..1023
    const int b = t >> 6;             // one wave per batch
    const int l = t & 63;

    const float cnt = c_g[b * LBL + l];
    const float q   = q_g[b * LBL + l];
    const float* sg = s_g + ((size_t)b * LBL + l) * CH;
    float sum2 = 0.f;
    #pragma unroll
    for (int c = 0; c < CH; ++c) sum2 = fmaf(sg[c], sg[c], sum2);

    float var_sum = 0.f;
    if (cnt > 1.f) var_sum = (q - sum2 / cnt) / (cnt - 1.f);

    float v       = (l != 0) ? var_sum : 0.f;
    float present = (l != 0 && cnt > 0.f) ? 1.f : 0.f;

    #pragma unroll
    for (int off = 32; off > 0; off >>= 1) {
        v       += __shfl_down(v, off);
        present += __shfl_down(present, off);
    }

    __shared__ float partial[BATCH];
    if (l == 0) partial[b] = v / (present + 1e-8f);
    __syncthreads();
    if (t == 0) {
        float acc = 0.f;
        #pragma unroll
        for (int i = 0; i < BATCH; ++i) acc += partial[i];
        out[0] = acc / (float)BATCH;
    }
}

// Fallback if ws is too small: one block per batch, LDS atomics (slow, correct).
__global__ __launch_bounds__(1024) void fallback_all(
    const float* __restrict__ x, const int* __restrict__ tg,
    float* __restrict__ out)
{
    __shared__ float s_l[CH][LBL];
    __shared__ float q_l[LBL];
    __shared__ float c_l[LBL];

    const int b   = blockIdx.x;
    const int tid = threadIdx.x;

    for (int i = tid; i < CH * LBL; i += 1024) (&s_l[0][0])[i] = 0.f;
    if (tid < LBL) { q_l[tid] = 0.f; c_l[tid] = 0.f; }
    __syncthreads();

    const float* xb = x  + (size_t)b * CH * PIX;
    const int*   tb = tg + (size_t)b * PIX;

    for (int base = 0; base < PIX; base += 1024 * 4) {
        const int p = base + tid * 4;
        const int4 lab = *reinterpret_cast<const int4*>(tb + p);
        float q0 = 0.f, q1 = 0.f, q2 = 0.f, q3 = 0.f;
        #pragma unroll 8
        for (int c = 0; c < CH; ++c) {
            const float4 v = *reinterpret_cast<const float4*>(xb + (size_t)c * PIX + p);
            unsafeAtomicAdd(&s_l[c][lab.x], v.x);
            unsafeAtomicAdd(&s_l[c][lab.y], v.y);
            unsafeAtomicAdd(&s_l[c][lab.z], v.z);
            unsafeAtomicAdd(&s_l[c][lab.w], v.w);
            q0 = fmaf(v.x, v.x, q0);
            q1 = fmaf(v.y, v.y, q1);
            q2 = fmaf(v.z, v.z, q2);
            q3 = fmaf(v.w, v.w, q3);
        }
        unsafeAtomicAdd(&q_l[lab.x], q0);
        unsafeAtomicAdd(&q_l[lab.y], q1);
        unsafeAtomicAdd(&q_l[lab.z], q2);
        unsafeAtomicAdd(&q_l[lab.w], q3);
        unsafeAtomicAdd(&c_l[lab.x], 1.f);
        unsafeAtomicAdd(&c_l[lab.y], 1.f);
        unsafeAtomicAdd(&c_l[lab.z], 1.f);
        unsafeAtomicAdd(&c_l[lab.w], 1.f);
    }
    __syncthreads();

    if (tid < LBL) {
        const int l = tid;
        const float cnt = c_l[l];
        const float q   = q_l[l];
        float sum2 = 0.f;
        #pragma unroll
        for (int c = 0; c < CH; ++c) sum2 = fmaf(s_l[c][l], s_l[c][l], sum2);
        float var_sum = 0.f;
        if (cnt > 1.f) var_sum = (q - sum2 / cnt) / (cnt - 1.f);
        float v       = (l != 0) ? var_sum : 0.f;
        float present = (l != 0 && cnt > 0.f) ? 1.f : 0.f;
        #pragma unroll
        for (int off = 32; off > 0; off >>= 1) {
            v       += __shfl_down(v, off);
            present += __shfl_down(present, off);
        }
        if (l == 0)
            unsafeAtomicAdd(out, v / (present + 1e-8f) / (float)BATCH);
    }
}

extern "C" void kernel_launch(void* const* d_in, const int* in_sizes, int n_in,
                              void* d_out, int out_size, void* d_ws, size_t ws_size,
                              hipStream_t stream)
{
    const float* x  = (const float*)d_in[0];
    const int*   tg = (const int*)d_in[1];
    float* out = (float*)d_out;
    float* ws  = (float*)d_ws;

    if (ws_size >= (size_t)WS_FLOATS * sizeof(float)) {
        zero_ws<<<(WS_FLOATS + TPB - 1) / TPB, TPB, 0, stream>>>(ws);
        dim3 grid(BPB, BATCH);
        seg_onehot_mfma<<<grid, TPB, 0, stream>>>(x, tg, ws, ws + Q_OFF, ws + C_OFF);
        finalize<<<1, 1024, 0, stream>>>(ws, ws + Q_OFF, ws + C_OFF, out);
    } else {
        hipMemsetAsync(d_out, 0, sizeof(float), stream);
        fallback_all<<<BATCH, 1024, 0, stream>>>(x, tg, out);
    }
}